// Round 3
// baseline (167.676 us; speedup 1.0000x reference)
//
#include <hip/hip_runtime.h>
#include <stdint.h>
#include <stddef.h>

typedef __attribute__((ext_vector_type(8))) short short8;
typedef __attribute__((ext_vector_type(4))) float f32x4;
typedef __attribute__((ext_vector_type(16))) float f32x16;
typedef __attribute__((ext_vector_type(4))) unsigned short us4;
typedef __attribute__((ext_vector_type(4))) unsigned u32x4;

#define DEVI static __device__ __forceinline__

DEVI unsigned short f2bf(float f) {
  unsigned u = __builtin_bit_cast(unsigned, f);
  u += 0x7FFFu + ((u >> 16) & 1u);
  return (unsigned short)(u >> 16);
}

DEVI f32x4 mfma16(short8 a, short8 b, f32x4 c) {
  return __builtin_amdgcn_mfma_f32_16x16x32_bf16(a, b, c, 0, 0, 0);
}

DEVI f32x16 mfma32(short8 a, short8 b, f32x16 c) {
  return __builtin_amdgcn_mfma_f32_32x32x16_bf16(a, b, c, 0, 0, 0);
}

DEVI unsigned cvtpk(float lo, float hi) {
  unsigned r;
  asm("v_cvt_pk_bf16_f32 %0, %1, %2" : "=v"(r) : "v"(lo), "v"(hi));
  return r;
}

DEVI void plswap(unsigned& a, unsigned& b) {
  asm("v_permlane32_swap_b32 %0, %1" : "+v"(a), "+v"(b));
}

DEVI f32x16 zero16() {
  f32x16 z;
#pragma unroll
  for (int i = 0; i < 16; ++i) z[i] = 0.f;
  return z;
}

// async global -> LDS, 16 bytes per lane (lane-linear LDS dest)
DEVI void glds16(const void* g, void* l) {
  __builtin_amdgcn_global_load_lds(
      (const __attribute__((address_space(1))) void*)g,
      (__attribute__((address_space(3))) void*)l, 16, 0, 0);
}

// ---------------- convert x (fp32 -> bf16) ----------------
__global__ __launch_bounds__(256) void k_cvt_x(const float* __restrict__ x,
                                               unsigned short* __restrict__ xb) {
  size_t i = ((size_t)blockIdx.x * 256 + threadIdx.x) * 8;
  f32x4 a = *(const f32x4*)(x + i);
  f32x4 b = *(const f32x4*)(x + i + 4);
  short8 v;
#pragma unroll
  for (int j = 0; j < 4; ++j) {
    v[j] = (short)f2bf(a[j]);
    v[4 + j] = (short)f2bf(b[j]);
  }
  *(short8*)(xb + i) = v;
}

// ---------------- transpose + convert W (K x N fp32 -> N x K bf16) ----------------
__global__ __launch_bounds__(256) void k_twT(const float* __restrict__ W,
                                             unsigned short* __restrict__ WT) {
  __shared__ float tile[64][65];
  const int n0 = blockIdx.x * 64, k0 = blockIdx.y * 64;
  const int t = threadIdx.x, rr = t >> 4, cc = (t & 15) * 4;
#pragma unroll
  for (int i = 0; i < 4; ++i) {
    int row = i * 16 + rr;
    f32x4 v = *(const f32x4*)(W + (size_t)(k0 + row) * 1024 + n0 + cc);
#pragma unroll
    for (int j = 0; j < 4; ++j) tile[row][cc + j] = v[j];
  }
  __syncthreads();
#pragma unroll
  for (int i = 0; i < 4; ++i) {
    int nrow = i * 16 + rr;
    us4 u;
#pragma unroll
    for (int j = 0; j < 4; ++j) u[j] = f2bf(tile[cc + j][nrow]);
    *(us4*)(WT + (size_t)(n0 + nrow) * 1024 + k0 + cc) = u;
  }
}

// ---------------- GEMM core (m97 structure): C(128x128) = A @ Bt^T ----------------
// LDS: A tile [128][64] bf16 linear @0, B tile @16KB. global_load_lds staging.
DEVI void gemm_core(const unsigned short* __restrict__ A,
                    const unsigned short* __restrict__ Bt,
                    int mt, int nt, char* lds, f32x4 (&acc)[4][4]) {
  const int t = threadIdx.x;
  const int l = t & 63, c = l & 15, g = l >> 4;
  const int w = t >> 6, wr = w >> 1, wc = w & 1;
  const int srow = t >> 3, scol = (t & 7) * 8;
  const unsigned short* Ab = A + (size_t)(mt * 128 + srow) * 1024 + scol;
  const unsigned short* Bb = Bt + (size_t)(nt * 128 + srow) * 1024 + scol;
  for (int k0 = 0; k0 < 1024; k0 += 64) {
#pragma unroll
    for (int i = 0; i < 4; ++i) {
      glds16(Ab + (size_t)i * 32 * 1024 + k0, lds + i * 4096 + t * 16);
      glds16(Bb + (size_t)i * 32 * 1024 + k0, lds + 16384 + i * 4096 + t * 16);
    }
    __syncthreads();
#pragma unroll
    for (int ks = 0; ks < 2; ++ks) {
      short8 af[4], bfr[4];
#pragma unroll
      for (int m = 0; m < 4; ++m)
        af[m] = *(const short8*)(lds + (wr * 64 + m * 16 + c) * 128 + ks * 64 + 16 * g);
#pragma unroll
      for (int n = 0; n < 4; ++n)
        bfr[n] = *(const short8*)(lds + 16384 + (wc * 64 + n * 16 + c) * 128 + ks * 64 + 16 * g);
#pragma unroll
      for (int m = 0; m < 4; ++m)
#pragma unroll
        for (int n = 0; n < 4; ++n) acc[m][n] = mfma16(af[m], bfr[n], acc[m][n]);
    }
    __syncthreads();
  }
}

// ---------------- QKV GEMM; Q pre-scaled by 0.125; V stored transposed ----------------
__global__ __launch_bounds__(256) void k_gemm_qkv(
    const unsigned short* __restrict__ A,
    const unsigned short* __restrict__ W0, const unsigned short* __restrict__ W1,
    const unsigned short* __restrict__ W2,
    const float* __restrict__ b0, const float* __restrict__ b1, const float* __restrict__ b2,
    unsigned short* __restrict__ O0, unsigned short* __restrict__ O1,
    unsigned short* __restrict__ O2) {
  __shared__ char lds[32768];
  const int z = blockIdx.z;
  const unsigned short* Bt = (z == 0) ? W0 : (z == 1) ? W1 : W2;
  const float* bias = (z == 0) ? b0 : (z == 1) ? b1 : b2;
  unsigned short* out = (z == 0) ? O0 : (z == 1) ? O1 : O2;
  f32x4 acc[4][4];
#pragma unroll
  for (int m = 0; m < 4; ++m)
#pragma unroll
    for (int n = 0; n < 4; ++n) acc[m][n] = (f32x4){0.f, 0.f, 0.f, 0.f};
  const int mt = blockIdx.y, nt = blockIdx.x;
  gemm_core(A, Bt, mt, nt, lds, acc);
  const int t = threadIdx.x, l = t & 63, c = l & 15, g = l >> 4;
  const int w = t >> 6, wr = w >> 1, wc = w & 1;
  if (z == 2) {
    // V^T layout: VT[((b*16+h)*64 + d) * 2048 + tt]
#pragma unroll
    for (int n = 0; n < 4; ++n) {
      int colg = nt * 128 + wc * 64 + n * 16 + c;
      float bvv = bias[colg];
      int h = colg >> 6, d = colg & 63;
#pragma unroll
      for (int m = 0; m < 4; ++m)
#pragma unroll
        for (int r = 0; r < 4; ++r) {
          int rowg = mt * 128 + wr * 64 + m * 16 + 4 * g + r;
          int b = rowg >> 11, tt = rowg & 2047;
          out[((size_t)(b * 16 + h) * 64 + d) * 2048 + tt] = f2bf(acc[m][n][r] + bvv);
        }
    }
  } else {
    const float sc = (z == 0) ? 0.125f : 1.0f;  // fold 1/sqrt(Dh) into Q
#pragma unroll
    for (int n = 0; n < 4; ++n) {
      int colg = nt * 128 + wc * 64 + n * 16 + c;
      float bvv = bias[colg];
      int h = colg >> 6, d = colg & 63;
#pragma unroll
      for (int m = 0; m < 4; ++m)
#pragma unroll
        for (int r = 0; r < 4; ++r) {
          int rowg = mt * 128 + wr * 64 + m * 16 + 4 * g + r;
          int b = rowg >> 11, tt = rowg & 2047;
          out[((size_t)(b * 16 + h) * 2048 + tt) * 64 + d] = f2bf((acc[m][n][r] + bvv) * sc);
        }
    }
  }
}

// ---------------- projection GEMM, fp32 epilogue ----------------
__global__ __launch_bounds__(256) void k_gemm_proj(const unsigned short* __restrict__ A,
                                                   const unsigned short* __restrict__ Bt,
                                                   const float* __restrict__ bias,
                                                   float* __restrict__ Y) {
  __shared__ char lds[32768];
  f32x4 acc[4][4];
#pragma unroll
  for (int m = 0; m < 4; ++m)
#pragma unroll
    for (int n = 0; n < 4; ++n) acc[m][n] = (f32x4){0.f, 0.f, 0.f, 0.f};
  const int mt = blockIdx.y, nt = blockIdx.x;
  gemm_core(A, Bt, mt, nt, lds, acc);
  const int t = threadIdx.x, l = t & 63, c = l & 15, g = l >> 4;
  const int w = t >> 6, wr = w >> 1, wc = w & 1;
#pragma unroll
  for (int n = 0; n < 4; ++n) {
    int colg = nt * 128 + wc * 64 + n * 16 + c;
    float bv = bias[colg];
#pragma unroll
    for (int m = 0; m < 4; ++m)
#pragma unroll
      for (int r = 0; r < 4; ++r) {
        int rowg = mt * 128 + wr * 64 + m * 16 + 4 * g + r;
        Y[(size_t)rowg * 1024 + colg] = acc[m][n][r] + bv;
      }
  }
}

// ---------------- flash attention v3: LDS-staged K/V, double-buffered, counted vmcnt ----
// Block = 4 waves x 32 q-rows = 128 q rows. K/V tiles (64 kv) staged once per block via
// global_load_lds with source-side XOR swizzle (c16 ^= row&7) => conflict-free ds_read_b128.
__global__ __launch_bounds__(256) void k_attn3(const unsigned short* __restrict__ Q,
                                               const unsigned short* __restrict__ K,
                                               const unsigned short* __restrict__ VT,
                                               unsigned short* __restrict__ O) {
  __shared__ char lds[32768];  // 2 bufs x (K 8KB | V 8KB)
  const int bid = blockIdx.x;
  const int half = bid >> 8, j = bid & 255;
  const int qt = half ? (j >> 5) : (15 - (j >> 5));  // long-first pairing
  const int bh = j & 31;
  const int t = threadIdx.x;
  const int w = t >> 6, l = t & 63;
  const int lq = l & 31, hi = l >> 5;
  const int q0 = qt * 128 + w * 32;
  const size_t kbase = (size_t)bh * 2048 * 64;  // K: (bh, t, d)
  const size_t vbase = (size_t)bh * 64 * 2048;  // VT: (bh, d, t)
  // staging geometry: round r covers rows r*32+srow, 16B block sc16 (src pre-swizzled)
  const int srow = t >> 3, sc16 = t & 7;
  const int sxor = (sc16 ^ (srow & 7)) * 8;  // swizzled source element offset
  const int my_nt = 2 * qt + 1 + (w >> 1);   // per-wave causal tile count
  const int NT = 2 * qt + 2;                 // block-uniform loop count
  // Q fragments (pre-scaled by 0.125 at GEMM epilogue)
  short8 qf[4];
#pragma unroll
  for (int ds = 0; ds < 4; ++ds)
    qf[ds] = *(const short8*)(Q + kbase + (size_t)(q0 + lq) * 64 + 16 * ds + 8 * hi);

  // stage tile kt into buffer buf
  auto STAGE = [&](int kt, int buf) {
    const unsigned short* Kt = K + kbase + (size_t)kt * 64 * 64;
    const unsigned short* Vt = VT + vbase + kt * 64;
    char* lb = lds + buf * 16384;
#pragma unroll
    for (int r = 0; r < 2; ++r) {
      int row = r * 32 + srow;
      glds16(Kt + (size_t)row * 64 + sxor, lb + r * 4096 + t * 16);
      glds16(Vt + (size_t)row * 2048 + sxor, lb + 8192 + r * 4096 + t * 16);
    }
  };

  f32x16 oacc[2];
  oacc[0] = zero16();
  oacc[1] = zero16();
  float m_s = -1e30f, l_s = 0.f;

  STAGE(0, 0);
  for (int kt = 0; kt < NT; ++kt) {
    const int nb = kt & 1;
    if (kt + 1 < NT) {
      STAGE(kt + 1, nb ^ 1);
      asm volatile("s_waitcnt vmcnt(4)" ::: "memory");
    } else {
      asm volatile("s_waitcnt vmcnt(0)" ::: "memory");
    }
    __builtin_amdgcn_s_barrier();
    asm volatile("" ::: "memory");
    if (kt < my_nt) {
      const char* lb = lds + nb * 16384;
      const int kv0 = kt * 64;
      // K fragments from LDS (swizzled)
      short8 kf0[4], kf1[4];
      const int rx = (lq & 7);
#pragma unroll
      for (int ds = 0; ds < 4; ++ds) {
        int blk = ((ds * 2 + hi) ^ rx) * 16;
        kf0[ds] = *(const short8*)(lb + lq * 128 + blk);
        kf1[ds] = *(const short8*)(lb + (lq + 32) * 128 + blk);
      }
      // S^T = K · Q^T : lane holds S[k][q=lq], k = (r&3)+8*(r>>2)+4*hi (+32 for st1)
      f32x16 st0 = zero16(), st1 = zero16();
#pragma unroll
      for (int ds = 0; ds < 4; ++ds) {
        st0 = mfma32(kf0[ds], qf[ds], st0);
        st1 = mfma32(kf1[ds], qf[ds], st1);
      }
      // V^T fragments from LDS (issue early; latency hides under softmax)
      short8 vf[2][4];
#pragma unroll
      for (int fd = 0; fd < 2; ++fd) {
        int d = fd * 32 + lq;
#pragma unroll
        for (int s = 0; s < 4; ++s)
          vf[fd][s] = *(const short8*)(lb + 8192 + d * 128 + (((s * 2 + hi) ^ rx) * 16));
      }
      // causal mask (wave-uniform last-tile branch)
      if (kt == my_nt - 1) {
        const int qg = q0 + lq;
#pragma unroll
        for (int r = 0; r < 16; ++r) {
          int kr = kv0 + (r & 3) + 8 * (r >> 2) + 4 * hi;
          if (kr > qg) st0[r] = -1e30f;
          if (kr + 32 > qg) st1[r] = -1e30f;
        }
      }
      // row max: tree (depth 5) + one cross-half exchange
      float mx;
      {
        float t8[8];
#pragma unroll
        for (int r = 0; r < 8; ++r)
          t8[r] = fmaxf(fmaxf(st0[r], st0[r + 8]), fmaxf(st1[r], st1[r + 8]));
        float a0 = fmaxf(t8[0], t8[4]), a1 = fmaxf(t8[1], t8[5]);
        float a2 = fmaxf(t8[2], t8[6]), a3 = fmaxf(t8[3], t8[7]);
        mx = fmaxf(fmaxf(a0, a1), fmaxf(a2, a3));
      }
      mx = fmaxf(mx, __shfl_xor(mx, 32, 64));
      // online-softmax update with defer-max (THR=8)
      if (!__all(mx - m_s <= 8.f)) {
        float mnew = fmaxf(m_s, mx);
        float corr = __expf(m_s - mnew);
        m_s = mnew;
        l_s *= corr;
#pragma unroll
        for (int r = 0; r < 16; ++r) {
          oacc[0][r] *= corr;
          oacc[1][r] *= corr;
        }
      }
      // p = exp(s - m), pack to bf16 words; tree psum
      unsigned Wp[2][4][2];
      float gs[8];
#pragma unroll
      for (int f = 0; f < 2; ++f)
#pragma unroll
        for (int m4 = 0; m4 < 4; ++m4) {
          float p0 = __expf((f ? st1 : st0)[4 * m4 + 0] - m_s);
          float p1 = __expf((f ? st1 : st0)[4 * m4 + 1] - m_s);
          float p2 = __expf((f ? st1 : st0)[4 * m4 + 2] - m_s);
          float p3 = __expf((f ? st1 : st0)[4 * m4 + 3] - m_s);
          gs[f * 4 + m4] = (p0 + p1) + (p2 + p3);
          Wp[f][m4][0] = cvtpk(p0, p1);
          Wp[f][m4][1] = cvtpk(p2, p3);
        }
      float ps = ((gs[0] + gs[1]) + (gs[2] + gs[3])) + ((gs[4] + gs[5]) + (gs[6] + gs[7]));
      ps += __shfl_xor(ps, 32, 64);
      l_s += ps;
      // O^T += V^T · P^T
#pragma unroll
      for (int s = 0; s < 4; ++s) {
        const int f = s >> 1, s2 = s & 1;
        unsigned a0 = Wp[f][2 * s2][0], b0 = Wp[f][2 * s2 + 1][0];
        unsigned a1 = Wp[f][2 * s2][1], b1 = Wp[f][2 * s2 + 1][1];
        plswap(a0, b0);
        plswap(a1, b1);
        u32x4 pw = {a0, a1, b0, b1};
        short8 pf = __builtin_bit_cast(short8, pw);
        oacc[0] = mfma32(vf[0][s], pf, oacc[0]);
        oacc[1] = mfma32(vf[1][s], pf, oacc[1]);
      }
    }
    __builtin_amdgcn_s_barrier();
    asm volatile("" ::: "memory");
  }
  // epilogue: lane owns q = lq. Store (B,T,1024) bf16.
  const float inv = 1.0f / l_s;
  const int b = bh >> 4, h = bh & 15;
  unsigned short* orow = O + ((size_t)b * 2048 + q0 + lq) * 1024 + h * 64 + 4 * hi;
#pragma unroll
  for (int f = 0; f < 2; ++f)
#pragma unroll
    for (int m4 = 0; m4 < 4; ++m4) {
      us4 u;
#pragma unroll
      for (int rr = 0; rr < 4; ++rr) u[rr] = f2bf(oacc[f][4 * m4 + rr] * inv);
      *(us4*)(orow + f * 32 + m4 * 8) = u;
    }
}

// ---------------- LayerNorm over last dim (1024), fp32 ----------------
__global__ __launch_bounds__(256) void k_ln(const float* __restrict__ Y,
                                            const float* __restrict__ gamma,
                                            const float* __restrict__ beta,
                                            float* __restrict__ out) {
  __shared__ float red[8];
  const int row = blockIdx.x, t = threadIdx.x, w = t >> 6, l = t & 63;
  const float* yr = Y + (size_t)row * 1024;
  f32x4 v = *(const f32x4*)(yr + t * 4);
  float s = v[0] + v[1] + v[2] + v[3];
  float ss = v[0] * v[0] + v[1] * v[1] + v[2] * v[2] + v[3] * v[3];
#pragma unroll
  for (int d = 1; d < 64; d <<= 1) {
    s += __shfl_xor(s, d, 64);
    ss += __shfl_xor(ss, d, 64);
  }
  if (l == 0) {
    red[w] = s;
    red[4 + w] = ss;
  }
  __syncthreads();
  s = red[0] + red[1] + red[2] + red[3];
  ss = red[4] + red[5] + red[6] + red[7];
  float mean = s * (1.f / 1024.f);
  float var = ss * (1.f / 1024.f) - mean * mean;
  float rstd = rsqrtf(var + 1e-5f);
  f32x4 gv = *(const f32x4*)(gamma + t * 4);
  f32x4 bv = *(const f32x4*)(beta + t * 4);
  f32x4 ov;
#pragma unroll
  for (int j = 0; j < 4; ++j) ov[j] = (v[j] - mean) * rstd * gv[j] + bv[j];
  *(f32x4*)(out + (size_t)row * 1024 + t * 4) = ov;
}

extern "C" void kernel_launch(void* const* d_in, const int* in_sizes, int n_in,
                              void* d_out, int out_size, void* d_ws, size_t ws_size,
                              hipStream_t stream) {
  (void)in_sizes; (void)n_in; (void)out_size; (void)ws_size;
  const float* x = (const float*)d_in[0];
  const float* Wq = (const float*)d_in[1];
  const float* bq = (const float*)d_in[2];
  const float* Wk = (const float*)d_in[3];
  const float* bk = (const float*)d_in[4];
  const float* Wv = (const float*)d_in[5];
  const float* bv = (const float*)d_in[6];
  const float* Wo = (const float*)d_in[7];
  const float* bo = (const float*)d_in[8];
  const float* gamma = (const float*)d_in[9];
  const float* beta = (const float*)d_in[10];
  char* ws = (char*)d_ws;
  const size_t MB = 1024 * 1024;
  unsigned short* xb = (unsigned short*)(ws);            // 8 MB
  unsigned short* WqT = (unsigned short*)(ws + 8 * MB);  // 2 MB each
  unsigned short* WkT = (unsigned short*)(ws + 10 * MB);
  unsigned short* WvT = (unsigned short*)(ws + 12 * MB);
  unsigned short* WoT = (unsigned short*)(ws + 14 * MB);
  unsigned short* Qb = (unsigned short*)(ws + 16 * MB);   // 8 MB each
  unsigned short* Kb = (unsigned short*)(ws + 24 * MB);
  unsigned short* VTb = (unsigned short*)(ws + 32 * MB);  // V transposed (BH,64,2048)
  unsigned short* Ob = (unsigned short*)(ws + 40 * MB);
  float* Y = (float*)(ws + 16 * MB);  // 16 MB, overlaps Qb/Kb (dead after attention)

  k_cvt_x<<<2048, 256, 0, stream>>>(x, xb);
  k_twT<<<dim3(16, 16), 256, 0, stream>>>(Wq, WqT);
  k_twT<<<dim3(16, 16), 256, 0, stream>>>(Wk, WkT);
  k_twT<<<dim3(16, 16), 256, 0, stream>>>(Wv, WvT);
  k_twT<<<dim3(16, 16), 256, 0, stream>>>(Wo, WoT);
  k_gemm_qkv<<<dim3(8, 32, 3), 256, 0, stream>>>(xb, WqT, WkT, WvT, bq, bk, bv, Qb, Kb, VTb);
  k_attn3<<<512, 256, 0, stream>>>(Qb, Kb, VTb, Ob);
  k_gemm_proj<<<dim3(8, 32), 256, 0, stream>>>(Ob, WoT, bo, Y);
  k_ln<<<4096, 256, 0, stream>>>(Y, gamma, beta, (float*)d_out);
}

// Round 4
// 139.164 us; speedup vs baseline: 1.2049x; 1.2049x over previous
//
#include <hip/hip_runtime.h>
#include <stdint.h>
#include <stddef.h>

typedef __attribute__((ext_vector_type(8))) short short8;
typedef __attribute__((ext_vector_type(4))) float f32x4;
typedef __attribute__((ext_vector_type(16))) float f32x16;
typedef __attribute__((ext_vector_type(4))) unsigned short us4;
typedef __attribute__((ext_vector_type(4))) unsigned u32x4;

#define DEVI static __device__ __forceinline__

DEVI unsigned short f2bf(float f) {
  unsigned u = __builtin_bit_cast(unsigned, f);
  u += 0x7FFFu + ((u >> 16) & 1u);
  return (unsigned short)(u >> 16);
}

DEVI f32x4 mfma16(short8 a, short8 b, f32x4 c) {
  return __builtin_amdgcn_mfma_f32_16x16x32_bf16(a, b, c, 0, 0, 0);
}

DEVI f32x16 mfma32(short8 a, short8 b, f32x16 c) {
  return __builtin_amdgcn_mfma_f32_32x32x16_bf16(a, b, c, 0, 0, 0);
}

DEVI unsigned cvtpk(float lo, float hi) {
  unsigned r;
  asm("v_cvt_pk_bf16_f32 %0, %1, %2" : "=v"(r) : "v"(lo), "v"(hi));
  return r;
}

DEVI void plswap(unsigned& a, unsigned& b) {
  asm("v_permlane32_swap_b32 %0, %1" : "+v"(a), "+v"(b));
}

DEVI f32x16 zero16() {
  f32x16 z;
#pragma unroll
  for (int i = 0; i < 16; ++i) z[i] = 0.f;
  return z;
}

// async global -> LDS, 16 bytes per lane (lane-linear LDS dest)
DEVI void glds16(const void* g, void* l) {
  __builtin_amdgcn_global_load_lds(
      (const __attribute__((address_space(1))) void*)g,
      (__attribute__((address_space(3))) void*)l, 16, 0, 0);
}

// ---------------- convert x (fp32 -> bf16) ----------------
__global__ __launch_bounds__(256) void k_cvt_x(const float* __restrict__ x,
                                               unsigned short* __restrict__ xb) {
  size_t i = ((size_t)blockIdx.x * 256 + threadIdx.x) * 8;
  f32x4 a = *(const f32x4*)(x + i);
  f32x4 b = *(const f32x4*)(x + i + 4);
  short8 v;
#pragma unroll
  for (int j = 0; j < 4; ++j) {
    v[j] = (short)f2bf(a[j]);
    v[4 + j] = (short)f2bf(b[j]);
  }
  *(short8*)(xb + i) = v;
}

// ---------------- transpose + convert W (K x N fp32 -> N x K bf16) ----------------
__global__ __launch_bounds__(256) void k_twT(const float* __restrict__ W,
                                             unsigned short* __restrict__ WT) {
  __shared__ float tile[64][65];
  const int n0 = blockIdx.x * 64, k0 = blockIdx.y * 64;
  const int t = threadIdx.x, rr = t >> 4, cc = (t & 15) * 4;
#pragma unroll
  for (int i = 0; i < 4; ++i) {
    int row = i * 16 + rr;
    f32x4 v = *(const f32x4*)(W + (size_t)(k0 + row) * 1024 + n0 + cc);
#pragma unroll
    for (int j = 0; j < 4; ++j) tile[row][cc + j] = v[j];
  }
  __syncthreads();
#pragma unroll
  for (int i = 0; i < 4; ++i) {
    int nrow = i * 16 + rr;
    us4 u;
#pragma unroll
    for (int j = 0; j < 4; ++j) u[j] = f2bf(tile[cc + j][nrow]);
    *(us4*)(WT + (size_t)(n0 + nrow) * 1024 + k0 + cc) = u;
  }
}

// ---------------- GEMM core v2: 2-phase double-buffered, counted drain ----------------
// C(128x128) = A(Mx1024) @ Bt(Nx1024)^T. LDS: 2 bufs x (A 16KB | B 16KB) = 64KB.
// SWAP=true computes C^T fragments (lane holds 4 consecutive output COLS) for
// column-contiguous epilogues; SWAP=false holds 4 consecutive output ROWS.
template <bool SWAP>
DEVI void gemm_core2(const unsigned short* __restrict__ A,
                     const unsigned short* __restrict__ Bt,
                     int mt, int nt, char* lds, f32x4 (&acc)[4][4]) {
  const int t = threadIdx.x;
  const int l = t & 63, c = l & 15, g = l >> 4;
  const int w = t >> 6, wr = w >> 1, wc = w & 1;
  const int srow = t >> 3, scol = (t & 7) * 8;
  const unsigned short* Ab = A + (size_t)(mt * 128 + srow) * 1024 + scol;
  const unsigned short* Bb = Bt + (size_t)(nt * 128 + srow) * 1024 + scol;

  auto STAGE = [&](int kt, int buf) {
    char* lb = lds + buf * 32768;
#pragma unroll
    for (int i = 0; i < 4; ++i) {
      glds16(Ab + (size_t)i * 32 * 1024 + kt * 64, lb + i * 4096 + t * 16);
      glds16(Bb + (size_t)i * 32 * 1024 + kt * 64, lb + 16384 + i * 4096 + t * 16);
    }
  };

  STAGE(0, 0);
  asm volatile("s_waitcnt vmcnt(0)" ::: "memory");
  __builtin_amdgcn_s_barrier();
  asm volatile("" ::: "memory");
  for (int kt = 0; kt < 16; ++kt) {
    const int cur = kt & 1;
    if (kt < 15) STAGE(kt + 1, cur ^ 1);  // next-tile loads fly under this tile's MFMA
    const char* lb = lds + cur * 32768;
#pragma unroll
    for (int ks = 0; ks < 2; ++ks) {
      short8 af[4], bfr[4];
#pragma unroll
      for (int m = 0; m < 4; ++m)
        af[m] = *(const short8*)(lb + (wr * 64 + m * 16 + c) * 128 + ks * 64 + 16 * g);
#pragma unroll
      for (int n = 0; n < 4; ++n)
        bfr[n] = *(const short8*)(lb + 16384 + (wc * 64 + n * 16 + c) * 128 + ks * 64 + 16 * g);
#pragma unroll
      for (int m = 0; m < 4; ++m)
#pragma unroll
        for (int n = 0; n < 4; ++n)
          acc[m][n] = SWAP ? mfma16(bfr[n], af[m], acc[m][n])
                           : mfma16(af[m], bfr[n], acc[m][n]);
    }
    asm volatile("s_waitcnt vmcnt(0)" ::: "memory");
    __builtin_amdgcn_s_barrier();
    asm volatile("" ::: "memory");
  }
}

// ---------------- fused QKV GEMM; Q pre-scaled by 0.125; V stored transposed ----------
// grid: x = mt (32), y = ntz (24). z = ntz>>3 selects Wq/Wk/Wv; xcd = mt%8 pins
// each XCD to a 1MB A-row slice (L2-resident across all 24 weight panels).
__global__ __launch_bounds__(256) void k_gemm_qkv(
    const unsigned short* __restrict__ A,
    const unsigned short* __restrict__ Wf,  // [3072][1024] = Wq^T | Wk^T | Wv^T
    const float* __restrict__ b0, const float* __restrict__ b1, const float* __restrict__ b2,
    unsigned short* __restrict__ O0, unsigned short* __restrict__ O1,
    unsigned short* __restrict__ O2) {
  __shared__ char lds[65536];
  const int mt = blockIdx.x, ntz = blockIdx.y;
  const int z = ntz >> 3, ntl = ntz & 7;
  const float* bias = (z == 0) ? b0 : (z == 1) ? b1 : b2;
  unsigned short* out = (z == 0) ? O0 : (z == 1) ? O1 : O2;
  f32x4 acc[4][4];
#pragma unroll
  for (int m = 0; m < 4; ++m)
#pragma unroll
    for (int n = 0; n < 4; ++n) acc[m][n] = (f32x4){0.f, 0.f, 0.f, 0.f};
  const int t = threadIdx.x, l = t & 63, c = l & 15, g = l >> 4;
  const int w = t >> 6, wr = w >> 1, wc = w & 1;
  if (z < 2) {
    gemm_core2<true>(A, Wf, mt, ntz, lds, acc);
    const float sc = (z == 0) ? 0.125f : 1.0f;  // fold 1/sqrt(Dh) into Q
#pragma unroll
    for (int n = 0; n < 4; ++n) {
      int colb = ntl * 128 + wc * 64 + n * 16 + 4 * g;  // within [0,1024)
      f32x4 bv4 = *(const f32x4*)(bias + colb);
      int h = colb >> 6, d = colb & 63;
#pragma unroll
      for (int m = 0; m < 4; ++m) {
        int rowg = mt * 128 + wr * 64 + m * 16 + c;
        int b = rowg >> 11, tt = rowg & 2047;
        us4 u;
#pragma unroll
        for (int r = 0; r < 4; ++r) u[r] = f2bf((acc[m][n][r] + bv4[r]) * sc);
        *(us4*)(out + ((size_t)(b * 16 + h) * 2048 + tt) * 64 + d) = u;
      }
    }
  } else {
    gemm_core2<false>(A, Wf, mt, ntz, lds, acc);
    // V^T layout: VT[((b*16+h)*64 + d) * 2048 + tt]; lane holds 4 consecutive tt
#pragma unroll
    for (int n = 0; n < 4; ++n) {
      int colg = ntl * 128 + wc * 64 + n * 16 + c;
      float bvv = bias[colg];
      int h = colg >> 6, d = colg & 63;
#pragma unroll
      for (int m = 0; m < 4; ++m) {
        int rowg = mt * 128 + wr * 64 + m * 16 + 4 * g;
        int b = rowg >> 11, tt = rowg & 2047;
        us4 u;
#pragma unroll
        for (int r = 0; r < 4; ++r) u[r] = f2bf(acc[m][n][r] + bvv);
        *(us4*)(out + ((size_t)(b * 16 + h) * 64 + d) * 2048 + tt) = u;
      }
    }
  }
}

// ---------------- projection GEMM, fp32 epilogue (column-contiguous f32x4) ----------
__global__ __launch_bounds__(256) void k_gemm_proj(const unsigned short* __restrict__ A,
                                                   const unsigned short* __restrict__ Bt,
                                                   const float* __restrict__ bias,
                                                   float* __restrict__ Y) {
  __shared__ char lds[65536];
  f32x4 acc[4][4];
#pragma unroll
  for (int m = 0; m < 4; ++m)
#pragma unroll
    for (int n = 0; n < 4; ++n) acc[m][n] = (f32x4){0.f, 0.f, 0.f, 0.f};
  const int mt = blockIdx.x, nt = blockIdx.y;
  gemm_core2<true>(A, Bt, mt, nt, lds, acc);
  const int t = threadIdx.x, l = t & 63, c = l & 15, g = l >> 4;
  const int w = t >> 6, wr = w >> 1, wc = w & 1;
#pragma unroll
  for (int n = 0; n < 4; ++n) {
    int colb = nt * 128 + wc * 64 + n * 16 + 4 * g;
    f32x4 bv4 = *(const f32x4*)(bias + colb);
#pragma unroll
    for (int m = 0; m < 4; ++m) {
      int rowg = mt * 128 + wr * 64 + m * 16 + c;
      f32x4 o;
#pragma unroll
      for (int r = 0; r < 4; ++r) o[r] = acc[m][n][r] + bv4[r];
      *(f32x4*)(Y + (size_t)rowg * 1024 + colb) = o;
    }
  }
}

// ---------------- flash attention v3: LDS-staged K/V, double-buffered, counted vmcnt ----
__global__ __launch_bounds__(256) void k_attn3(const unsigned short* __restrict__ Q,
                                               const unsigned short* __restrict__ K,
                                               const unsigned short* __restrict__ VT,
                                               unsigned short* __restrict__ O) {
  __shared__ char lds[32768];  // 2 bufs x (K 8KB | V 8KB)
  const int bid = blockIdx.x;
  const int half = bid >> 8, j = bid & 255;
  const int qt = half ? (j >> 5) : (15 - (j >> 5));  // long-first pairing
  const int bh = j & 31;
  const int t = threadIdx.x;
  const int w = t >> 6, l = t & 63;
  const int lq = l & 31, hi = l >> 5;
  const int q0 = qt * 128 + w * 32;
  const size_t kbase = (size_t)bh * 2048 * 64;  // K: (bh, t, d)
  const size_t vbase = (size_t)bh * 64 * 2048;  // VT: (bh, d, t)
  const int srow = t >> 3, sc16 = t & 7;
  const int sxor = (sc16 ^ (srow & 7)) * 8;  // swizzled source element offset
  const int my_nt = 2 * qt + 1 + (w >> 1);   // per-wave causal tile count
  const int NT = 2 * qt + 2;                 // block-uniform loop count
  short8 qf[4];
#pragma unroll
  for (int ds = 0; ds < 4; ++ds)
    qf[ds] = *(const short8*)(Q + kbase + (size_t)(q0 + lq) * 64 + 16 * ds + 8 * hi);

  auto STAGE = [&](int kt, int buf) {
    const unsigned short* Kt = K + kbase + (size_t)kt * 64 * 64;
    const unsigned short* Vt = VT + vbase + kt * 64;
    char* lb = lds + buf * 16384;
#pragma unroll
    for (int r = 0; r < 2; ++r) {
      int row = r * 32 + srow;
      glds16(Kt + (size_t)row * 64 + sxor, lb + r * 4096 + t * 16);
      glds16(Vt + (size_t)row * 2048 + sxor, lb + 8192 + r * 4096 + t * 16);
    }
  };

  f32x16 oacc[2];
  oacc[0] = zero16();
  oacc[1] = zero16();
  float m_s = -1e30f, l_s = 0.f;

  STAGE(0, 0);
  for (int kt = 0; kt < NT; ++kt) {
    const int nb = kt & 1;
    if (kt + 1 < NT) {
      STAGE(kt + 1, nb ^ 1);
      asm volatile("s_waitcnt vmcnt(4)" ::: "memory");
    } else {
      asm volatile("s_waitcnt vmcnt(0)" ::: "memory");
    }
    __builtin_amdgcn_s_barrier();
    asm volatile("" ::: "memory");
    if (kt < my_nt) {
      const char* lb = lds + nb * 16384;
      const int kv0 = kt * 64;
      short8 kf0[4], kf1[4];
      const int rx = (lq & 7);
#pragma unroll
      for (int ds = 0; ds < 4; ++ds) {
        int blk = ((ds * 2 + hi) ^ rx) * 16;
        kf0[ds] = *(const short8*)(lb + lq * 128 + blk);
        kf1[ds] = *(const short8*)(lb + (lq + 32) * 128 + blk);
      }
      f32x16 st0 = zero16(), st1 = zero16();
#pragma unroll
      for (int ds = 0; ds < 4; ++ds) {
        st0 = mfma32(kf0[ds], qf[ds], st0);
        st1 = mfma32(kf1[ds], qf[ds], st1);
      }
      short8 vf[2][4];
#pragma unroll
      for (int fd = 0; fd < 2; ++fd) {
        int d = fd * 32 + lq;
#pragma unroll
        for (int s = 0; s < 4; ++s)
          vf[fd][s] = *(const short8*)(lb + 8192 + d * 128 + (((s * 2 + hi) ^ rx) * 16));
      }
      if (kt == my_nt - 1) {
        const int qg = q0 + lq;
#pragma unroll
        for (int r = 0; r < 16; ++r) {
          int kr = kv0 + (r & 3) + 8 * (r >> 2) + 4 * hi;
          if (kr > qg) st0[r] = -1e30f;
          if (kr + 32 > qg) st1[r] = -1e30f;
        }
      }
      float mx;
      {
        float t8[8];
#pragma unroll
        for (int r = 0; r < 8; ++r)
          t8[r] = fmaxf(fmaxf(st0[r], st0[r + 8]), fmaxf(st1[r], st1[r + 8]));
        float a0 = fmaxf(t8[0], t8[4]), a1 = fmaxf(t8[1], t8[5]);
        float a2 = fmaxf(t8[2], t8[6]), a3 = fmaxf(t8[3], t8[7]);
        mx = fmaxf(fmaxf(a0, a1), fmaxf(a2, a3));
      }
      mx = fmaxf(mx, __shfl_xor(mx, 32, 64));
      if (!__all(mx - m_s <= 8.f)) {
        float mnew = fmaxf(m_s, mx);
        float corr = __expf(m_s - mnew);
        m_s = mnew;
        l_s *= corr;
#pragma unroll
        for (int r = 0; r < 16; ++r) {
          oacc[0][r] *= corr;
          oacc[1][r] *= corr;
        }
      }
      unsigned Wp[2][4][2];
      float gs[8];
#pragma unroll
      for (int f = 0; f < 2; ++f)
#pragma unroll
        for (int m4 = 0; m4 < 4; ++m4) {
          float p0 = __expf((f ? st1 : st0)[4 * m4 + 0] - m_s);
          float p1 = __expf((f ? st1 : st0)[4 * m4 + 1] - m_s);
          float p2 = __expf((f ? st1 : st0)[4 * m4 + 2] - m_s);
          float p3 = __expf((f ? st1 : st0)[4 * m4 + 3] - m_s);
          gs[f * 4 + m4] = (p0 + p1) + (p2 + p3);
          Wp[f][m4][0] = cvtpk(p0, p1);
          Wp[f][m4][1] = cvtpk(p2, p3);
        }
      float ps = ((gs[0] + gs[1]) + (gs[2] + gs[3])) + ((gs[4] + gs[5]) + (gs[6] + gs[7]));
      ps += __shfl_xor(ps, 32, 64);
      l_s += ps;
#pragma unroll
      for (int s = 0; s < 4; ++s) {
        const int f = s >> 1, s2 = s & 1;
        unsigned a0 = Wp[f][2 * s2][0], b0 = Wp[f][2 * s2 + 1][0];
        unsigned a1 = Wp[f][2 * s2][1], b1 = Wp[f][2 * s2 + 1][1];
        plswap(a0, b0);
        plswap(a1, b1);
        u32x4 pw = {a0, a1, b0, b1};
        short8 pf = __builtin_bit_cast(short8, pw);
        oacc[0] = mfma32(vf[0][s], pf, oacc[0]);
        oacc[1] = mfma32(vf[1][s], pf, oacc[1]);
      }
    }
    __builtin_amdgcn_s_barrier();
    asm volatile("" ::: "memory");
  }
  const float inv = 1.0f / l_s;
  const int b = bh >> 4, h = bh & 15;
  unsigned short* orow = O + ((size_t)b * 2048 + q0 + lq) * 1024 + h * 64 + 4 * hi;
#pragma unroll
  for (int f = 0; f < 2; ++f)
#pragma unroll
    for (int m4 = 0; m4 < 4; ++m4) {
      us4 u;
#pragma unroll
      for (int rr = 0; rr < 4; ++rr) u[rr] = f2bf(oacc[f][4 * m4 + rr] * inv);
      *(us4*)(orow + f * 32 + m4 * 8) = u;
    }
}

// ---------------- LayerNorm over last dim (1024), fp32 ----------------
__global__ __launch_bounds__(256) void k_ln(const float* __restrict__ Y,
                                            const float* __restrict__ gamma,
                                            const float* __restrict__ beta,
                                            float* __restrict__ out) {
  __shared__ float red[8];
  const int row = blockIdx.x, t = threadIdx.x, w = t >> 6, l = t & 63;
  const float* yr = Y + (size_t)row * 1024;
  f32x4 v = *(const f32x4*)(yr + t * 4);
  float s = v[0] + v[1] + v[2] + v[3];
  float ss = v[0] * v[0] + v[1] * v[1] + v[2] * v[2] + v[3] * v[3];
#pragma unroll
  for (int d = 1; d < 64; d <<= 1) {
    s += __shfl_xor(s, d, 64);
    ss += __shfl_xor(ss, d, 64);
  }
  if (l == 0) {
    red[w] = s;
    red[4 + w] = ss;
  }
  __syncthreads();
  s = red[0] + red[1] + red[2] + red[3];
  ss = red[4] + red[5] + red[6] + red[7];
  float mean = s * (1.f / 1024.f);
  float var = ss * (1.f / 1024.f) - mean * mean;
  float rstd = rsqrtf(var + 1e-5f);
  f32x4 gv = *(const f32x4*)(gamma + t * 4);
  f32x4 bv = *(const f32x4*)(beta + t * 4);
  f32x4 ov;
#pragma unroll
  for (int j = 0; j < 4; ++j) ov[j] = (v[j] - mean) * rstd * gv[j] + bv[j];
  *(f32x4*)(out + (size_t)row * 1024 + t * 4) = ov;
}

extern "C" void kernel_launch(void* const* d_in, const int* in_sizes, int n_in,
                              void* d_out, int out_size, void* d_ws, size_t ws_size,
                              hipStream_t stream) {
  (void)in_sizes; (void)n_in; (void)out_size; (void)ws_size;
  const float* x = (const float*)d_in[0];
  const float* Wq = (const float*)d_in[1];
  const float* bq = (const float*)d_in[2];
  const float* Wk = (const float*)d_in[3];
  const float* bk = (const float*)d_in[4];
  const float* Wv = (const float*)d_in[5];
  const float* bv = (const float*)d_in[6];
  const float* Wo = (const float*)d_in[7];
  const float* bo = (const float*)d_in[8];
  const float* gamma = (const float*)d_in[9];
  const float* beta = (const float*)d_in[10];
  char* ws = (char*)d_ws;
  const size_t MB = 1024 * 1024;
  unsigned short* xb = (unsigned short*)(ws);            // 8 MB
  unsigned short* WqT = (unsigned short*)(ws + 8 * MB);  // 2 MB each; Wq|Wk|Wv contiguous
  unsigned short* WkT = (unsigned short*)(ws + 10 * MB);
  unsigned short* WvT = (unsigned short*)(ws + 12 * MB);
  unsigned short* WoT = (unsigned short*)(ws + 14 * MB);
  unsigned short* Qb = (unsigned short*)(ws + 16 * MB);   // 8 MB each
  unsigned short* Kb = (unsigned short*)(ws + 24 * MB);
  unsigned short* VTb = (unsigned short*)(ws + 32 * MB);  // V transposed (BH,64,2048)
  unsigned short* Ob = (unsigned short*)(ws + 40 * MB);
  float* Y = (float*)(ws + 16 * MB);  // 16 MB, overlaps Qb/Kb (dead after attention)

  k_cvt_x<<<2048, 256, 0, stream>>>(x, xb);
  k_twT<<<dim3(16, 16), 256, 0, stream>>>(Wq, WqT);
  k_twT<<<dim3(16, 16), 256, 0, stream>>>(Wk, WkT);
  k_twT<<<dim3(16, 16), 256, 0, stream>>>(Wv, WvT);
  k_twT<<<dim3(16, 16), 256, 0, stream>>>(Wo, WoT);
  k_gemm_qkv<<<dim3(32, 24), 256, 0, stream>>>(xb, WqT, bq, bk, bv, Qb, Kb, VTb);
  k_attn3<<<512, 256, 0, stream>>>(Qb, Kb, VTb, Ob);
  k_gemm_proj<<<dim3(32, 8), 256, 0, stream>>>(Ob, WoT, bo, Y);
  k_ln<<<4096, 256, 0, stream>>>(Y, gamma, beta, (float*)d_out);
}

// Round 5
// 116.947 us; speedup vs baseline: 1.4338x; 1.1900x over previous
//
#include <hip/hip_runtime.h>
#include <stdint.h>
#include <stddef.h>

typedef __attribute__((ext_vector_type(8))) short short8;
typedef __attribute__((ext_vector_type(4))) float f32x4;
typedef __attribute__((ext_vector_type(16))) float f32x16;
typedef __attribute__((ext_vector_type(4))) unsigned short us4;
typedef __attribute__((ext_vector_type(4))) unsigned u32x4;

#define DEVI static __device__ __forceinline__

DEVI unsigned short f2bf(float f) {
  unsigned u = __builtin_bit_cast(unsigned, f);
  u += 0x7FFFu + ((u >> 16) & 1u);
  return (unsigned short)(u >> 16);
}

DEVI f32x4 mfma16(short8 a, short8 b, f32x4 c) {
  return __builtin_amdgcn_mfma_f32_16x16x32_bf16(a, b, c, 0, 0, 0);
}

DEVI f32x16 mfma32(short8 a, short8 b, f32x16 c) {
  return __builtin_amdgcn_mfma_f32_32x32x16_bf16(a, b, c, 0, 0, 0);
}

DEVI unsigned cvtpk(float lo, float hi) {
  unsigned r;
  asm("v_cvt_pk_bf16_f32 %0, %1, %2" : "=v"(r) : "v"(lo), "v"(hi));
  return r;
}

DEVI void plswap(unsigned& a, unsigned& b) {
  asm("v_permlane32_swap_b32 %0, %1" : "+v"(a), "+v"(b));
}

DEVI float ex2(float x) {  // 2^x, single v_exp_f32
  float r;
  asm("v_exp_f32 %0, %1" : "=v"(r) : "v"(x));
  return r;
}

DEVI float mx3(float a, float b, float c) {
  float r;
  asm("v_max3_f32 %0, %1, %2, %3" : "=v"(r) : "v"(a), "v"(b), "v"(c));
  return r;
}

DEVI f32x16 zero16() {
  f32x16 z;
#pragma unroll
  for (int i = 0; i < 16; ++i) z[i] = 0.f;
  return z;
}

// async global -> LDS, 16 bytes per lane (lane-linear LDS dest)
DEVI void glds16(const void* g, void* l) {
  __builtin_amdgcn_global_load_lds(
      (const __attribute__((address_space(1))) void*)g,
      (__attribute__((address_space(3))) void*)l, 16, 0, 0);
}

// ---------------- convert x (fp32 -> bf16) ----------------
__global__ __launch_bounds__(256) void k_cvt_x(const float* __restrict__ x,
                                               unsigned short* __restrict__ xb) {
  size_t i = ((size_t)blockIdx.x * 256 + threadIdx.x) * 8;
  f32x4 a = *(const f32x4*)(x + i);
  f32x4 b = *(const f32x4*)(x + i + 4);
  short8 v;
#pragma unroll
  for (int j = 0; j < 4; ++j) {
    v[j] = (short)f2bf(a[j]);
    v[4 + j] = (short)f2bf(b[j]);
  }
  *(short8*)(xb + i) = v;
}

// ------------- transpose + convert all 4 weights (K x N fp32 -> N x K bf16) -------------
__global__ __launch_bounds__(256) void k_twT4(const float* __restrict__ W0,
                                              const float* __restrict__ W1,
                                              const float* __restrict__ W2,
                                              const float* __restrict__ W3,
                                              unsigned short* __restrict__ WT) {
  __shared__ float tile[64][65];
  const int z = blockIdx.z;
  const float* W = (z == 0) ? W0 : (z == 1) ? W1 : (z == 2) ? W2 : W3;
  unsigned short* out = WT + (size_t)z * 1024 * 1024;
  const int n0 = blockIdx.x * 64, k0 = blockIdx.y * 64;
  const int t = threadIdx.x, rr = t >> 4, cc = (t & 15) * 4;
#pragma unroll
  for (int i = 0; i < 4; ++i) {
    int row = i * 16 + rr;
    f32x4 v = *(const f32x4*)(W + (size_t)(k0 + row) * 1024 + n0 + cc);
#pragma unroll
    for (int j = 0; j < 4; ++j) tile[row][cc + j] = v[j];
  }
  __syncthreads();
#pragma unroll
  for (int i = 0; i < 4; ++i) {
    int nrow = i * 16 + rr;
    us4 u;
#pragma unroll
    for (int j = 0; j < 4; ++j) u[j] = f2bf(tile[cc + j][nrow]);
    *(us4*)(out + (size_t)(n0 + nrow) * 1024 + k0 + cc) = u;
  }
}

// ---------------- GEMM core v3: 2-phase dbuf + T2 XOR swizzle ----------------
// C(128x128) = A(Mx1024) @ Bt(Nx1024)^T. LDS: 2 bufs x (A 16KB | B 16KB) = 64KB.
// LDS[row][slot16] holds global slot (slot^ (row&7)) -> conflict-free ds_read_b128.
template <bool SWAP>
DEVI void gemm_core2(const unsigned short* __restrict__ A,
                     const unsigned short* __restrict__ Bt,
                     int mt, int nt, char* lds, f32x4 (&acc)[4][4]) {
  const int t = threadIdx.x;
  const int l = t & 63, c = l & 15, g = l >> 4;
  const int w = t >> 6, wr = w >> 1, wc = w & 1;
  const int srow = t >> 3;
  const int sxor = (((t & 7) ^ (srow & 7))) * 8;  // pre-swizzled source column
  const unsigned short* Ab = A + (size_t)(mt * 128 + srow) * 1024 + sxor;
  const unsigned short* Bb = Bt + (size_t)(nt * 128 + srow) * 1024 + sxor;
  const int key = (c & 7);  // read-side XOR key (row&7 == c&7 for all m,n)

  auto STAGE = [&](int kt, int buf) {
    char* lb = lds + buf * 32768;
#pragma unroll
    for (int i = 0; i < 4; ++i) {
      glds16(Ab + (size_t)i * 32 * 1024 + kt * 64, lb + i * 4096 + t * 16);
      glds16(Bb + (size_t)i * 32 * 1024 + kt * 64, lb + 16384 + i * 4096 + t * 16);
    }
  };

  STAGE(0, 0);
  asm volatile("s_waitcnt vmcnt(0)" ::: "memory");
  __builtin_amdgcn_s_barrier();
  asm volatile("" ::: "memory");
  for (int kt = 0; kt < 16; ++kt) {
    const int cur = kt & 1;
    if (kt < 15) STAGE(kt + 1, cur ^ 1);  // next-tile loads fly under this tile's MFMA
    const char* lb = lds + cur * 32768;
#pragma unroll
    for (int ks = 0; ks < 2; ++ks) {
      short8 af[4], bfr[4];
#pragma unroll
      for (int m = 0; m < 4; ++m)
        af[m] = *(const short8*)(lb + (wr * 64 + m * 16 + c) * 128 +
                                 ((ks * 4 + g) ^ key) * 16);
#pragma unroll
      for (int n = 0; n < 4; ++n)
        bfr[n] = *(const short8*)(lb + 16384 + (wc * 64 + n * 16 + c) * 128 +
                                  ((ks * 4 + g) ^ key) * 16);
#pragma unroll
      for (int m = 0; m < 4; ++m)
#pragma unroll
        for (int n = 0; n < 4; ++n)
          acc[m][n] = SWAP ? mfma16(bfr[n], af[m], acc[m][n])
                           : mfma16(af[m], bfr[n], acc[m][n]);
    }
    asm volatile("s_waitcnt vmcnt(0)" ::: "memory");
    __builtin_amdgcn_s_barrier();
    asm volatile("" ::: "memory");
  }
}

// ---------------- fused QKV GEMM; Q pre-scaled by 0.125*log2(e); V stored transposed ----
__global__ __launch_bounds__(256) void k_gemm_qkv(
    const unsigned short* __restrict__ A,
    const unsigned short* __restrict__ Wf,  // [3072][1024] = Wq^T | Wk^T | Wv^T
    const float* __restrict__ b0, const float* __restrict__ b1, const float* __restrict__ b2,
    unsigned short* __restrict__ O0, unsigned short* __restrict__ O1,
    unsigned short* __restrict__ O2) {
  __shared__ char lds[65536];
  const int mt = blockIdx.x, ntz = blockIdx.y;
  const int z = ntz >> 3, ntl = ntz & 7;
  const float* bias = (z == 0) ? b0 : (z == 1) ? b1 : b2;
  unsigned short* out = (z == 0) ? O0 : (z == 1) ? O1 : O2;
  f32x4 acc[4][4];
#pragma unroll
  for (int m = 0; m < 4; ++m)
#pragma unroll
    for (int n = 0; n < 4; ++n) acc[m][n] = (f32x4){0.f, 0.f, 0.f, 0.f};
  const int t = threadIdx.x, l = t & 63, c = l & 15, g = l >> 4;
  const int w = t >> 6, wr = w >> 1, wc = w & 1;
  if (z < 2) {
    gemm_core2<true>(A, Wf, mt, ntz, lds, acc);
    // fold 1/sqrt(Dh) * log2(e) into Q so softmax uses 2^x directly
    const float sc = (z == 0) ? 0.18033688011f : 1.0f;
#pragma unroll
    for (int n = 0; n < 4; ++n) {
      int colb = ntl * 128 + wc * 64 + n * 16 + 4 * g;  // within [0,1024)
      f32x4 bv4 = *(const f32x4*)(bias + colb);
      int h = colb >> 6, d = colb & 63;
#pragma unroll
      for (int m = 0; m < 4; ++m) {
        int rowg = mt * 128 + wr * 64 + m * 16 + c;
        int b = rowg >> 11, tt = rowg & 2047;
        us4 u;
#pragma unroll
        for (int r = 0; r < 4; ++r) u[r] = f2bf((acc[m][n][r] + bv4[r]) * sc);
        *(us4*)(out + ((size_t)(b * 16 + h) * 2048 + tt) * 64 + d) = u;
      }
    }
  } else {
    gemm_core2<false>(A, Wf, mt, ntz, lds, acc);
    // V^T layout: VT[((b*16+h)*64 + d) * 2048 + tt]; lane holds 4 consecutive tt
#pragma unroll
    for (int n = 0; n < 4; ++n) {
      int colg = ntl * 128 + wc * 64 + n * 16 + c;
      float bvv = bias[colg];
      int h = colg >> 6, d = colg & 63;
#pragma unroll
      for (int m = 0; m < 4; ++m) {
        int rowg = mt * 128 + wr * 64 + m * 16 + 4 * g;
        int b = rowg >> 11, tt = rowg & 2047;
        us4 u;
#pragma unroll
        for (int r = 0; r < 4; ++r) u[r] = f2bf(acc[m][n][r] + bvv);
        *(us4*)(out + ((size_t)(b * 16 + h) * 64 + d) * 2048 + tt) = u;
      }
    }
  }
}

// ---------------- projection GEMM, fp32 epilogue (column-contiguous f32x4) ----------
__global__ __launch_bounds__(256) void k_gemm_proj(const unsigned short* __restrict__ A,
                                                   const unsigned short* __restrict__ Bt,
                                                   const float* __restrict__ bias,
                                                   float* __restrict__ Y) {
  __shared__ char lds[65536];
  f32x4 acc[4][4];
#pragma unroll
  for (int m = 0; m < 4; ++m)
#pragma unroll
    for (int n = 0; n < 4; ++n) acc[m][n] = (f32x4){0.f, 0.f, 0.f, 0.f};
  const int mt = blockIdx.x, nt = blockIdx.y;
  gemm_core2<true>(A, Bt, mt, nt, lds, acc);
  const int t = threadIdx.x, l = t & 63, c = l & 15, g = l >> 4;
  const int w = t >> 6, wr = w >> 1, wc = w & 1;
#pragma unroll
  for (int n = 0; n < 4; ++n) {
    int colb = nt * 128 + wc * 64 + n * 16 + 4 * g;
    f32x4 bv4 = *(const f32x4*)(bias + colb);
#pragma unroll
    for (int m = 0; m < 4; ++m) {
      int rowg = mt * 128 + wr * 64 + m * 16 + c;
      f32x4 o;
#pragma unroll
      for (int r = 0; r < 4; ++r) o[r] = acc[m][n][r] + bv4[r];
      *(f32x4*)(Y + (size_t)rowg * 1024 + colb) = o;
    }
  }
}

// ---------------- flash attention v4: 2-wave blocks, 1 barrier/tile, exp2 softmax ------
// Block = 2 waves x 32 q rows = 64 q rows. Grid 1024 = 32 qt x 32 bh, long-first pairing.
// NT = qt+1 is block-uniform (no divergent tile counts). K/V staged via global_load_lds
// with source-side XOR swizzle; single s_barrier per KV tile.
__global__ __launch_bounds__(128) void k_attn4(const unsigned short* __restrict__ Q,
                                               const unsigned short* __restrict__ K,
                                               const unsigned short* __restrict__ VT,
                                               unsigned short* __restrict__ O) {
  __shared__ char lds[32768];  // 2 bufs x (K 8KB | V 8KB)
  const int bid = blockIdx.x;
  const int half = bid >> 9, j = bid & 511;
  const int qt = half ? (j >> 5) : (31 - (j >> 5));  // long-first pairing
  const int bh = j & 31;
  const int t = threadIdx.x;
  const int w = t >> 6, l = t & 63;
  const int lq = l & 31, hi = l >> 5;
  const int q0 = qt * 64 + w * 32;
  const size_t kbase = (size_t)bh * 2048 * 64;  // K: (bh, t, d)
  const size_t vbase = (size_t)bh * 64 * 2048;  // VT: (bh, d, t)
  const int srow = t >> 3;                       // 0..15
  const int sx = ((t & 7) ^ (srow & 7)) * 8;     // swizzled source column (elements)
  const int NT = qt + 1;                         // uniform causal tile count

  // Q fragments (pre-scaled by 0.125*log2e at GEMM epilogue)
  short8 qf[4];
#pragma unroll
  for (int ds = 0; ds < 4; ++ds)
    qf[ds] = *(const short8*)(Q + kbase + (size_t)(q0 + lq) * 64 + 16 * ds + 8 * hi);

  auto STAGE = [&](int kt, int buf) {
    const unsigned short* Kt = K + kbase + (size_t)kt * 4096;
    const unsigned short* Vt = VT + vbase + kt * 64;
    char* lb = lds + buf * 16384;
#pragma unroll
    for (int i = 0; i < 4; ++i) {
      int row = i * 16 + srow;
      glds16(Kt + (size_t)row * 64 + sx, lb + i * 2048 + t * 16);
      glds16(Vt + (size_t)row * 2048 + sx, lb + 8192 + i * 2048 + t * 16);
    }
  };

  f32x16 oacc[2];
  oacc[0] = zero16();
  oacc[1] = zero16();
  float m_s = -1e30f, l_s = 0.f;
  const int rx = lq & 7;

  STAGE(0, 0);
  for (int kt = 0; kt < NT; ++kt) {
    // drain this tile's staging (latency hidden under previous compute), sync, prefetch
    asm volatile("s_waitcnt vmcnt(0)" ::: "memory");
    __builtin_amdgcn_s_barrier();
    asm volatile("" ::: "memory");
    if (kt + 1 < NT) STAGE(kt + 1, (kt + 1) & 1);
    const char* lb = lds + (kt & 1) * 16384;
    const int kv0 = kt * 64;
    // K fragments (swizzled)
    short8 kf0[4], kf1[4];
#pragma unroll
    for (int ds = 0; ds < 4; ++ds) {
      int blk = ((ds * 2 + hi) ^ rx) * 16;
      kf0[ds] = *(const short8*)(lb + lq * 128 + blk);
      kf1[ds] = *(const short8*)(lb + (lq + 32) * 128 + blk);
    }
    // S^T = K · Q^T (units: log2) : lane holds S[k][q=lq]
    f32x16 st0 = zero16(), st1 = zero16();
    __builtin_amdgcn_s_setprio(1);
#pragma unroll
    for (int ds = 0; ds < 4; ++ds) {
      st0 = mfma32(kf0[ds], qf[ds], st0);
      st1 = mfma32(kf1[ds], qf[ds], st1);
    }
    __builtin_amdgcn_s_setprio(0);
    // V^T fragments (issue early; latency hides under softmax)
    short8 vf[2][4];
#pragma unroll
    for (int fd = 0; fd < 2; ++fd) {
      int d = fd * 32 + lq;
#pragma unroll
      for (int s = 0; s < 4; ++s)
        vf[fd][s] = *(const short8*)(lb + 8192 + d * 128 + (((s * 2 + hi) ^ rx) * 16));
    }
    // causal mask (wave-uniform last-tile branch)
    if (kt == NT - 1) {
      const int qg = q0 + lq;
#pragma unroll
      for (int r = 0; r < 16; ++r) {
        int kr = kv0 + (r & 3) + 8 * (r >> 2) + 4 * hi;
        if (kr > qg) st0[r] = -1e30f;
        if (kr + 32 > qg) st1[r] = -1e30f;
      }
    }
    // row max: v_max3 tree + one cross-half exchange
    float a8[8];
#pragma unroll
    for (int r = 0; r < 8; ++r)
      a8[r] = fmaxf(mx3(st0[r], st0[r + 8], st1[r]), st1[r + 8]);
    float mxv = mx3(mx3(a8[0], a8[1], a8[2]), mx3(a8[3], a8[4], a8[5]),
                    fmaxf(a8[6], a8[7]));
    mxv = fmaxf(mxv, __shfl_xor(mxv, 32, 64));
    // online-softmax update with defer-max (THR = 8*log2e)
    if (!__all(mxv - m_s <= 11.5413f)) {
      float mnew = fmaxf(m_s, mxv);
      float corr = ex2(m_s - mnew);
      m_s = mnew;
      l_s *= corr;
#pragma unroll
      for (int r = 0; r < 16; ++r) {
        oacc[0][r] *= corr;
        oacc[1][r] *= corr;
      }
    }
    // p = 2^(s - m), pack to bf16 words; tree psum
    unsigned Wp[2][4][2];
    float gs[8];
#pragma unroll
    for (int f = 0; f < 2; ++f)
#pragma unroll
      for (int m4 = 0; m4 < 4; ++m4) {
        float p0 = ex2((f ? st1 : st0)[4 * m4 + 0] - m_s);
        float p1 = ex2((f ? st1 : st0)[4 * m4 + 1] - m_s);
        float p2 = ex2((f ? st1 : st0)[4 * m4 + 2] - m_s);
        float p3 = ex2((f ? st1 : st0)[4 * m4 + 3] - m_s);
        gs[f * 4 + m4] = (p0 + p1) + (p2 + p3);
        Wp[f][m4][0] = cvtpk(p0, p1);
        Wp[f][m4][1] = cvtpk(p2, p3);
      }
    float ps = ((gs[0] + gs[1]) + (gs[2] + gs[3])) + ((gs[4] + gs[5]) + (gs[6] + gs[7]));
    ps += __shfl_xor(ps, 32, 64);
    l_s += ps;
    // O^T += V^T · P^T
    __builtin_amdgcn_s_setprio(1);
#pragma unroll
    for (int s = 0; s < 4; ++s) {
      const int f = s >> 1, s2 = s & 1;
      unsigned a0 = Wp[f][2 * s2][0], b0 = Wp[f][2 * s2 + 1][0];
      unsigned a1 = Wp[f][2 * s2][1], b1 = Wp[f][2 * s2 + 1][1];
      plswap(a0, b0);
      plswap(a1, b1);
      u32x4 pw = {a0, a1, b0, b1};
      short8 pf = __builtin_bit_cast(short8, pw);
      oacc[0] = mfma32(vf[0][s], pf, oacc[0]);
      oacc[1] = mfma32(vf[1][s], pf, oacc[1]);
    }
    __builtin_amdgcn_s_setprio(0);
  }
  // epilogue: lane owns q = lq. Store (B,T,1024) bf16.
  const float inv = 1.0f / l_s;
  const int b = bh >> 4, h = bh & 15;
  unsigned short* orow = O + ((size_t)b * 2048 + q0 + lq) * 1024 + h * 64 + 4 * hi;
#pragma unroll
  for (int f = 0; f < 2; ++f)
#pragma unroll
    for (int m4 = 0; m4 < 4; ++m4) {
      us4 u;
#pragma unroll
      for (int rr = 0; rr < 4; ++rr) u[rr] = f2bf(oacc[f][4 * m4 + rr] * inv);
      *(us4*)(orow + f * 32 + m4 * 8) = u;
    }
}

// ---------------- LayerNorm over last dim (1024), fp32 ----------------
__global__ __launch_bounds__(256) void k_ln(const float* __restrict__ Y,
                                            const float* __restrict__ gamma,
                                            const float* __restrict__ beta,
                                            float* __restrict__ out) {
  __shared__ float red[8];
  const int row = blockIdx.x, t = threadIdx.x, w = t >> 6, l = t & 63;
  const float* yr = Y + (size_t)row * 1024;
  f32x4 v = *(const f32x4*)(yr + t * 4);
  float s = v[0] + v[1] + v[2] + v[3];
  float ss = v[0] * v[0] + v[1] * v[1] + v[2] * v[2] + v[3] * v[3];
#pragma unroll
  for (int d = 1; d < 64; d <<= 1) {
    s += __shfl_xor(s, d, 64);
    ss += __shfl_xor(ss, d, 64);
  }
  if (l == 0) {
    red[w] = s;
    red[4 + w] = ss;
  }
  __syncthreads();
  s = red[0] + red[1] + red[2] + red[3];
  ss = red[4] + red[5] + red[6] + red[7];
  float mean = s * (1.f / 1024.f);
  float var = ss * (1.f / 1024.f) - mean * mean;
  float rstd = rsqrtf(var + 1e-5f);
  f32x4 gv = *(const f32x4*)(gamma + t * 4);
  f32x4 bv = *(const f32x4*)(beta + t * 4);
  f32x4 ov;
#pragma unroll
  for (int j = 0; j < 4; ++j) ov[j] = (v[j] - mean) * rstd * gv[j] + bv[j];
  *(f32x4*)(out + (size_t)row * 1024 + t * 4) = ov;
}

extern "C" void kernel_launch(void* const* d_in, const int* in_sizes, int n_in,
                              void* d_out, int out_size, void* d_ws, size_t ws_size,
                              hipStream_t stream) {
  (void)in_sizes; (void)n_in; (void)out_size; (void)ws_size;
  const float* x = (const float*)d_in[0];
  const float* Wq = (const float*)d_in[1];
  const float* bq = (const float*)d_in[2];
  const float* Wk = (const float*)d_in[3];
  const float* bk = (const float*)d_in[4];
  const float* Wv = (const float*)d_in[5];
  const float* bv = (const float*)d_in[6];
  const float* Wo = (const float*)d_in[7];
  const float* bo = (const float*)d_in[8];
  const float* gamma = (const float*)d_in[9];
  const float* beta = (const float*)d_in[10];
  char* ws = (char*)d_ws;
  const size_t MB = 1024 * 1024;
  unsigned short* xb = (unsigned short*)(ws);            // 8 MB
  unsigned short* WT = (unsigned short*)(ws + 8 * MB);   // 8 MB: WqT|WkT|WvT|WoT
  unsigned short* WoT = (unsigned short*)(ws + 14 * MB);
  unsigned short* Qb = (unsigned short*)(ws + 16 * MB);   // 8 MB each
  unsigned short* Kb = (unsigned short*)(ws + 24 * MB);
  unsigned short* VTb = (unsigned short*)(ws + 32 * MB);  // V transposed (BH,64,2048)
  unsigned short* Ob = (unsigned short*)(ws + 40 * MB);
  float* Y = (float*)(ws + 16 * MB);  // 16 MB, overlaps Qb/Kb (dead after attention)

  k_cvt_x<<<2048, 256, 0, stream>>>(x, xb);
  k_twT4<<<dim3(16, 16, 4), 256, 0, stream>>>(Wq, Wk, Wv, Wo, WT);
  k_gemm_qkv<<<dim3(32, 24), 256, 0, stream>>>(xb, WT, bq, bk, bv, Qb, Kb, VTb);
  k_attn4<<<1024, 128, 0, stream>>>(Qb, Kb, VTb, Ob);
  k_gemm_proj<<<dim3(32, 8), 256, 0, stream>>>(Ob, WoT, bo, Y);
  k_ln<<<4096, 256, 0, stream>>>(Y, gamma, beta, (float*)d_out);
}